// Round 1
// baseline (148.520 us; speedup 1.0000x reference)
//
#include <hip/hip_runtime.h>
#include <cstddef>

#define ZDIM 64
#define PDIM 4096          // Z*Z
#define PB   256           // p's per block (= blockDim)
#define BCHUNK 32          // batch rows per block

__device__ __forceinline__ float fast_tanh(float x) {
    // tanh(x) = 1 - 2/(exp(2x)+1); exp(2x) = exp2(x * 2*log2(e))
    float e = __builtin_amdgcn_exp2f(x * 2.8853900817779268f);
    float r = __builtin_amdgcn_rcpf(e + 1.0f);
    return __builtin_fmaf(-2.0f, r, 1.0f);
}

__device__ __forceinline__ float fast_sigmoid(float x) {
    float e = __builtin_amdgcn_exp2f(x * -1.4426950408889634f);
    return __builtin_amdgcn_rcpf(e + 1.0f);
}

__global__ void __launch_bounds__(PB) pair_mlp_kernel(
    const float* __restrict__ x,
    const float* __restrict__ W1, const float* __restrict__ b1,
    const float* __restrict__ g1, const float* __restrict__ be1,
    const float* __restrict__ W2, const float* __restrict__ b2,
    const float* __restrict__ g2, const float* __restrict__ be2,
    const float* __restrict__ W3, const float* __restrict__ b3,
    float* __restrict__ out, int nbc)
{
    const int tid = threadIdx.x;
    const int pb  = blockIdx.x / nbc;          // which p-tile (0..15)
    const int bc  = blockIdx.x - pb * nbc;     // which batch chunk
    const int p   = pb * PB + tid;
    const int z   = __builtin_amdgcn_readfirstlane(p >> 6);  // wave-uniform
    const int zp  = p & 63;

    // ---------------- load per-p weights (once per block) ----------------
    const float4* W1v = reinterpret_cast<const float4*>(W1 + (size_t)p * 8);
    const float4 w1x = W1v[0];   // W1[p][0][0..3]
    const float4 w1y = W1v[1];   // W1[p][1][0..3]
    const float4 b1v  = reinterpret_cast<const float4*>(b1)[p];
    const float4 g1v  = reinterpret_cast<const float4*>(g1)[p];
    const float4 be1v = reinterpret_cast<const float4*>(be1)[p];

    float w2[4][4];
    {
        const float4* W2v = reinterpret_cast<const float4*>(W2 + (size_t)p * 16);
        #pragma unroll
        for (int i = 0; i < 4; ++i) {
            float4 r = W2v[i];
            w2[i][0] = r.x; w2[i][1] = r.y; w2[i][2] = r.z; w2[i][3] = r.w;
        }
    }
    const float4 b2v  = reinterpret_cast<const float4*>(b2)[p];
    const float4 g2v  = reinterpret_cast<const float4*>(g2)[p];
    const float4 be2v = reinterpret_cast<const float4*>(be2)[p];
    const float4 w3v  = reinterpret_cast<const float4*>(W3)[p];
    const float  b3s  = b3[p];

    const float w1aa[4] = {w1x.x, w1x.y, w1x.z, w1x.w};
    const float w1ba[4] = {w1y.x, w1y.y, w1y.z, w1y.w};
    const float b1a[4]  = {b1v.x, b1v.y, b1v.z, b1v.w};
    const float g1a[4]  = {g1v.x, g1v.y, g1v.z, g1v.w};
    const float be1a[4] = {be1v.x, be1v.y, be1v.z, be1v.w};
    const float b2a[4]  = {b2v.x, b2v.y, b2v.z, b2v.w};
    const float g2a[4]  = {g2v.x, g2v.y, g2v.z, g2v.w};
    const float be2a[4] = {be2v.x, be2v.y, be2v.z, be2v.w};
    const float w3a[4]  = {w3v.x, w3v.y, w3v.z, w3v.w};

    // ---- fold LN1 affine into layer 2, LN2 affine into layer 3 ----
    // n1[i] = (t[i]-m)*rs*g1[i] + be1[i]
    // k[j]  = sum_i n1[i]*W2[i][j] + b2[j]
    //       = rs*(sum_i t[i]*w2g[i][j] - m*cs2[j]) + b2p[j]
    float w2g[4][4], cs2[4], b2p[4];
    #pragma unroll
    for (int j = 0; j < 4; ++j) { cs2[j] = 0.f; b2p[j] = b2a[j]; }
    #pragma unroll
    for (int i = 0; i < 4; ++i) {
        #pragma unroll
        for (int j = 0; j < 4; ++j) {
            float wg = g1a[i] * w2[i][j];
            w2g[i][j] = wg;
            cs2[j] += wg;
            b2p[j] = __builtin_fmaf(be1a[i], w2[i][j], b2p[j]);
        }
    }
    float w3g[4], cs3 = 0.f, b3p = b3s;
    #pragma unroll
    for (int j = 0; j < 4; ++j) {
        w3g[j] = g2a[j] * w3a[j];
        cs3 += w3g[j];
        b3p = __builtin_fmaf(be2a[j], w3a[j], b3p);
    }

    // ---------------- batch loop ----------------
    const int b0 = bc * BCHUNK;
    for (int it = 0; it < BCHUNK; ++it) {
        const int b = b0 + it;
        const float a = x[b * ZDIM + z];    // wave-uniform -> s_load
        const float c = x[b * ZDIM + zp];   // coalesced 256B per wave

        // layer 1 + tanh
        float t[4];
        #pragma unroll
        for (int i = 0; i < 4; ++i)
            t[i] = fast_tanh(__builtin_fmaf(a, w1aa[i],
                         __builtin_fmaf(c, w1ba[i], b1a[i])));

        // LN1 moments
        float s1 = (t[0] + t[1]) + (t[2] + t[3]);
        float s2 = __builtin_fmaf(t[0], t[0],
                   __builtin_fmaf(t[1], t[1],
                   __builtin_fmaf(t[2], t[2], t[3] * t[3])));
        float m  = 0.25f * s1;
        float v  = __builtin_fmaf(0.25f, s2, -(m * m));
        float rs = __builtin_amdgcn_rsqf(v + 1e-5f);

        // layer 2 (LN1 folded) + tanh
        float u[4];
        #pragma unroll
        for (int j = 0; j < 4; ++j) {
            float acc = -m * cs2[j];
            #pragma unroll
            for (int i = 0; i < 4; ++i)
                acc = __builtin_fmaf(t[i], w2g[i][j], acc);
            u[j] = fast_tanh(__builtin_fmaf(rs, acc, b2p[j]));
        }

        // LN2 moments
        float q1 = (u[0] + u[1]) + (u[2] + u[3]);
        float q2 = __builtin_fmaf(u[0], u[0],
                   __builtin_fmaf(u[1], u[1],
                   __builtin_fmaf(u[2], u[2], u[3] * u[3])));
        float m2  = 0.25f * q1;
        float v2  = __builtin_fmaf(0.25f, q2, -(m2 * m2));
        float rs2 = __builtin_amdgcn_rsqf(v2 + 1e-5f);

        // layer 3 (LN2 folded) + sigmoid
        float acc = -m2 * cs3;
        #pragma unroll
        for (int j = 0; j < 4; ++j)
            acc = __builtin_fmaf(u[j], w3g[j], acc);

        out[(size_t)b * PDIM + p] = fast_sigmoid(__builtin_fmaf(rs2, acc, b3p));
    }
}

extern "C" void kernel_launch(void* const* d_in, const int* in_sizes, int n_in,
                              void* d_out, int out_size, void* d_ws, size_t ws_size,
                              hipStream_t stream) {
    const float* x   = (const float*)d_in[0];
    const float* W1  = (const float*)d_in[1];
    const float* b1  = (const float*)d_in[2];
    const float* g1  = (const float*)d_in[3];
    const float* be1 = (const float*)d_in[4];
    const float* W2  = (const float*)d_in[5];
    const float* b2  = (const float*)d_in[6];
    const float* g2  = (const float*)d_in[7];
    const float* be2 = (const float*)d_in[8];
    const float* W3  = (const float*)d_in[9];
    const float* b3  = (const float*)d_in[10];
    float* out = (float*)d_out;

    const int B   = in_sizes[0] / ZDIM;     // 4096
    const int nbc = B / BCHUNK;             // 128
    const int grid = (PDIM / PB) * nbc;     // 16 * 128 = 2048

    hipLaunchKernelGGL(pair_mlp_kernel, dim3(grid), dim3(PB), 0, stream,
                       x, W1, b1, g1, be1, W2, b2, g2, be2, W3, b3, out, nbc);
}

// Round 2
// 137.096 us; speedup vs baseline: 1.0833x; 1.0833x over previous
//
#include <hip/hip_runtime.h>
#include <cstddef>

#define ZDIM 64
#define PDIM 4096          // Z*Z
#define PB   256           // p's per block (= blockDim)
#define BCHUNK 32          // batch rows per block (processed 2 at a time)

typedef float v2f __attribute__((ext_vector_type(2)));

__device__ __forceinline__ v2f pkfma(v2f a, v2f b, v2f c) {
    return __builtin_elementwise_fma(a, b, c);
}

__device__ __forceinline__ float fast_tanh(float x) {
    // tanh(x) = 1 - 2/(exp(2x)+1); exp(2x) = exp2(x * 2*log2(e))
    float e = __builtin_amdgcn_exp2f(x * 2.8853900817779268f);
    float r = __builtin_amdgcn_rcpf(e + 1.0f);
    return __builtin_fmaf(-2.0f, r, 1.0f);
}

__device__ __forceinline__ float fast_sigmoid(float x) {
    float e = __builtin_amdgcn_exp2f(x * -1.4426950408889634f);
    return __builtin_amdgcn_rcpf(e + 1.0f);
}

__device__ __forceinline__ v2f tanh2(v2f h) {
    v2f r; r.x = fast_tanh(h.x); r.y = fast_tanh(h.y); return r;
}

__global__ void __launch_bounds__(PB, 2) pair_mlp_kernel(
    const float* __restrict__ x,
    const float* __restrict__ W1, const float* __restrict__ b1,
    const float* __restrict__ g1, const float* __restrict__ be1,
    const float* __restrict__ W2, const float* __restrict__ b2,
    const float* __restrict__ g2, const float* __restrict__ be2,
    const float* __restrict__ W3, const float* __restrict__ b3,
    float* __restrict__ out, int nbc)
{
    const int tid = threadIdx.x;
    const int pb  = blockIdx.x / nbc;          // which p-tile (0..15)
    const int bc  = blockIdx.x - pb * nbc;     // which batch chunk
    const int p   = pb * PB + tid;
    const int z   = __builtin_amdgcn_readfirstlane(p >> 6);  // wave-uniform
    const int zp  = p & 63;

    // ---------------- load per-p weights (once per block) ----------------
    const float4* W1v = reinterpret_cast<const float4*>(W1 + (size_t)p * 8);
    const float4 w1x = W1v[0];   // W1[p][0][0..3]
    const float4 w1y = W1v[1];   // W1[p][1][0..3]
    const float4 b1v  = reinterpret_cast<const float4*>(b1)[p];
    const float4 g1v  = reinterpret_cast<const float4*>(g1)[p];
    const float4 be1v = reinterpret_cast<const float4*>(be1)[p];

    float w2[4][4];
    {
        const float4* W2v = reinterpret_cast<const float4*>(W2 + (size_t)p * 16);
        #pragma unroll
        for (int i = 0; i < 4; ++i) {
            float4 r = W2v[i];
            w2[i][0] = r.x; w2[i][1] = r.y; w2[i][2] = r.z; w2[i][3] = r.w;
        }
    }
    const float4 b2v  = reinterpret_cast<const float4*>(b2)[p];
    const float4 g2v  = reinterpret_cast<const float4*>(g2)[p];
    const float4 be2v = reinterpret_cast<const float4*>(be2)[p];
    const float4 w3v  = reinterpret_cast<const float4*>(W3)[p];
    const float  b3s  = b3[p];

    const float w1aa[4] = {w1x.x, w1x.y, w1x.z, w1x.w};
    const float w1ba[4] = {w1y.x, w1y.y, w1y.z, w1y.w};
    const float b1a[4]  = {b1v.x, b1v.y, b1v.z, b1v.w};
    const float g1a[4]  = {g1v.x, g1v.y, g1v.z, g1v.w};
    const float be1a[4] = {be1v.x, be1v.y, be1v.z, be1v.w};
    const float b2a[4]  = {b2v.x, b2v.y, b2v.z, b2v.w};
    const float g2a[4]  = {g2v.x, g2v.y, g2v.z, g2v.w};
    const float be2a[4] = {be2v.x, be2v.y, be2v.z, be2v.w};
    const float w3a[4]  = {w3v.x, w3v.y, w3v.z, w3v.w};

    // ---- fold LN1 affine into layer 2, LN2 affine into layer 3 ----
    float w2g[4][4], cs2[4], b2p[4];
    #pragma unroll
    for (int j = 0; j < 4; ++j) { cs2[j] = 0.f; b2p[j] = b2a[j]; }
    #pragma unroll
    for (int i = 0; i < 4; ++i) {
        #pragma unroll
        for (int j = 0; j < 4; ++j) {
            float wg = g1a[i] * w2[i][j];
            w2g[i][j] = wg;
            cs2[j] += wg;
            b2p[j] = __builtin_fmaf(be1a[i], w2[i][j], b2p[j]);
        }
    }
    float w3g[4], cs3 = 0.f, b3p = b3s;
    #pragma unroll
    for (int j = 0; j < 4; ++j) {
        w3g[j] = g2a[j] * w3a[j];
        cs3 += w3g[j];
        b3p = __builtin_fmaf(be2a[j], w3a[j], b3p);
    }

    // ---- duplicate folded weights into v2 registers (once) ----
    v2f w1aa2[4], w1ba2[4], b1a2[4], w2g2[4][4], cs2_2[4], b2p2[4], w3g2[4];
    #pragma unroll
    for (int i = 0; i < 4; ++i) {
        w1aa2[i].x = w1aa[i]; w1aa2[i].y = w1aa[i];
        w1ba2[i].x = w1ba[i]; w1ba2[i].y = w1ba[i];
        b1a2[i].x  = b1a[i];  b1a2[i].y  = b1a[i];
        cs2_2[i].x = cs2[i];  cs2_2[i].y = cs2[i];
        b2p2[i].x  = b2p[i];  b2p2[i].y  = b2p[i];
        w3g2[i].x  = w3g[i];  w3g2[i].y  = w3g[i];
        #pragma unroll
        for (int j = 0; j < 4; ++j) { w2g2[i][j].x = w2g[i][j]; w2g2[i][j].y = w2g[i][j]; }
    }
    v2f cs3_2; cs3_2.x = cs3; cs3_2.y = cs3;
    v2f b3p2;  b3p2.x  = b3p; b3p2.y  = b3p;

    // ---------------- batch loop: 2 rows per iteration ----------------
    const int b0 = bc * BCHUNK;
    for (int it = 0; it < BCHUNK; it += 2) {
        const int b = b0 + it;
        v2f av, cv;
        av.x = x[b * ZDIM + z];          // wave-uniform -> s_load
        av.y = x[(b + 1) * ZDIM + z];
        cv.x = x[b * ZDIM + zp];         // coalesced 256B per wave
        cv.y = x[(b + 1) * ZDIM + zp];

        // layer 1 + tanh (packed fma, scalar tanh)
        v2f t[4];
        #pragma unroll
        for (int i = 0; i < 4; ++i)
            t[i] = tanh2(pkfma(av, w1aa2[i], pkfma(cv, w1ba2[i], b1a2[i])));

        // LN1 moments (packed)
        v2f s1 = (t[0] + t[1]) + (t[2] + t[3]);
        v2f s2 = pkfma(t[0], t[0], pkfma(t[1], t[1], pkfma(t[2], t[2], t[3] * t[3])));
        v2f m  = s1 * 0.25f;
        v2f mn = s1 * -0.25f;
        v2f var = pkfma(mn, m, s2 * 0.25f) + 1e-5f;
        v2f rs; rs.x = __builtin_amdgcn_rsqf(var.x); rs.y = __builtin_amdgcn_rsqf(var.y);

        // layer 2 (LN1 folded) + tanh
        v2f u[4];
        #pragma unroll
        for (int j = 0; j < 4; ++j) {
            v2f acc = mn * cs2_2[j];
            #pragma unroll
            for (int i = 0; i < 4; ++i)
                acc = pkfma(t[i], w2g2[i][j], acc);
            u[j] = tanh2(pkfma(rs, acc, b2p2[j]));
        }

        // LN2 moments (packed)
        v2f q1 = (u[0] + u[1]) + (u[2] + u[3]);
        v2f q2 = pkfma(u[0], u[0], pkfma(u[1], u[1], pkfma(u[2], u[2], u[3] * u[3])));
        v2f m2  = q1 * 0.25f;
        v2f mn2 = q1 * -0.25f;
        v2f var2 = pkfma(mn2, m2, q2 * 0.25f) + 1e-5f;
        v2f rs2; rs2.x = __builtin_amdgcn_rsqf(var2.x); rs2.y = __builtin_amdgcn_rsqf(var2.y);

        // layer 3 (LN2 folded) + sigmoid
        v2f acc = mn2 * cs3_2;
        #pragma unroll
        for (int j = 0; j < 4; ++j)
            acc = pkfma(u[j], w3g2[j], acc);
        v2f s = pkfma(rs2, acc, b3p2);

        out[(size_t)b * PDIM + p]       = fast_sigmoid(s.x);
        out[(size_t)(b + 1) * PDIM + p] = fast_sigmoid(s.y);
    }
}

extern "C" void kernel_launch(void* const* d_in, const int* in_sizes, int n_in,
                              void* d_out, int out_size, void* d_ws, size_t ws_size,
                              hipStream_t stream) {
    const float* x   = (const float*)d_in[0];
    const float* W1  = (const float*)d_in[1];
    const float* b1  = (const float*)d_in[2];
    const float* g1  = (const float*)d_in[3];
    const float* be1 = (const float*)d_in[4];
    const float* W2  = (const float*)d_in[5];
    const float* b2  = (const float*)d_in[6];
    const float* g2  = (const float*)d_in[7];
    const float* be2 = (const float*)d_in[8];
    const float* W3  = (const float*)d_in[9];
    const float* b3  = (const float*)d_in[10];
    float* out = (float*)d_out;

    const int B   = in_sizes[0] / ZDIM;     // 4096
    const int nbc = B / BCHUNK;             // 128
    const int grid = (PDIM / PB) * nbc;     // 16 * 128 = 2048

    hipLaunchKernelGGL(pair_mlp_kernel, dim3(grid), dim3(PB), 0, stream,
                       x, W1, b1, g1, be1, W2, b2, g2, be2, W3, b3, out, nbc);
}